// Round 2
// baseline (185.681 us; speedup 1.0000x reference)
//
#include <hip/hip_runtime.h>
#include <hip/hip_cooperative_groups.h>

namespace cg = cooperative_groups;

#define N_TOK 8192
#define DIM   512
#define FDIM  128
#define BM    32

typedef __attribute__((ext_vector_type(8))) short short8;
typedef __attribute__((ext_vector_type(4))) float floatx4;

__device__ inline short f2bf(float f) {
    union { float f; unsigned u; } v; v.f = f;
    unsigned r = (v.u + 0x7FFF + ((v.u >> 16) & 1)) >> 16;  // RNE, inputs are finite
    return (short)r;
}

// Single cooperative kernel, 256 blocks x 512 threads.
// Pre-sync:  waves 0-3 route 32 tokens/block (8 serial/wave, fp32 exact) and emit
//            bf16 xbf; waves 4-7 repack w1a/w1b/w2 into MFMA B-fragment order
//            (3 frag-units/wave x 1024 waves = 3072 units). Block-aggregated
//            bucket append (atomics on 8 counters, 256 ops/counter).
// grid.sync()
// Post-sync: FFN tiles (BM=32 rows, 8 waves) pulled from an atomic work queue
//            (~260 tiles over 256 blocks -> ragged tail auto-balanced).
__global__ __launch_bounds__(512, 2) void k_fused(
    const float* __restrict__ x,
    const float* __restrict__ wn0, const float* __restrict__ bn0,
    const float* __restrict__ wn1, const float* __restrict__ bn1,
    const float* __restrict__ wn2, const float* __restrict__ bn2,
    const float* __restrict__ w1a, const float* __restrict__ w1b,
    const float* __restrict__ w2,
    const float* __restrict__ b1a, const float* __restrict__ b1b,
    const float* __restrict__ b2,
    int* __restrict__ counts, int* __restrict__ lists, int* __restrict__ queue,
    short* __restrict__ pw1a, short* __restrict__ pw1b, short* __restrict__ pw2,
    short* __restrict__ xbf,
    float* __restrict__ out)
{
    const int blk  = blockIdx.x;
    const int t    = threadIdx.x;
    const int wave = t >> 6, lane = t & 63;

    __shared__ int   sleafs[32];
    __shared__ int   toks[BM];
    __shared__ short xs[BM][DIM + 8];    // +8 pad: row stride 1040B -> banks shift 4/row
    __shared__ short hs[BM][FDIM + 8];
    __shared__ int   s_it;

    // ================= pre-sync =================
    if (wave < 4) {
        // ---- routing: tokens [blk*32 + wave*8, +8), fp32 exact ----
        const int d0 = lane * 8;
        float v0[8], v1[16], v2[32];
        #pragma unroll
        for (int j = 0; j < 8; ++j)  v0[j] = wn0[d0 + j];
        #pragma unroll
        for (int j = 0; j < 16; ++j) v1[j] = wn1[d0 * 2 + j];   // v1[j*2+c] = wn1[(d0+j)*2+c]
        #pragma unroll
        for (int j = 0; j < 32; ++j) v2[j] = wn2[d0 * 4 + j];   // v2[j*4+c]
        const float b0s = bn0[0];
        const float b1s[2] = {bn1[0], bn1[1]};
        const float b2s[4] = {bn2[0], bn2[1], bn2[2], bn2[3]};
        #pragma unroll 2
        for (int i = 0; i < 8; ++i) {
            const int tok = blk * 32 + wave * 8 + i;
            const float4* xp = (const float4*)(x + tok * DIM + d0);
            const float4 xa = xp[0], xb = xp[1];
            const float xv[8] = {xa.x, xa.y, xa.z, xa.w, xb.x, xb.y, xb.z, xb.w};
            // bf16 side-channel for the FFN phase (same RNE bits as before)
            short8 xo;
            #pragma unroll
            for (int j = 0; j < 8; ++j) xo[j] = f2bf(xv[j]);
            *(short8*)(xbf + (size_t)tok * DIM + d0) = xo;
            float a0 = 0.f, a1[2] = {0.f, 0.f}, a2[4] = {0.f, 0.f, 0.f, 0.f};
            #pragma unroll
            for (int j = 0; j < 8; ++j) {
                a0    += xv[j] * v0[j];
                a1[0] += xv[j] * v1[j * 2];     a1[1] += xv[j] * v1[j * 2 + 1];
                a2[0] += xv[j] * v2[j * 4];     a2[1] += xv[j] * v2[j * 4 + 1];
                a2[2] += xv[j] * v2[j * 4 + 2]; a2[3] += xv[j] * v2[j * 4 + 3];
            }
            #pragma unroll
            for (int off = 32; off >= 1; off >>= 1) {
                a0    += __shfl_xor(a0, off, 64);
                a1[0] += __shfl_xor(a1[0], off, 64);
                a1[1] += __shfl_xor(a1[1], off, 64);
                a2[0] += __shfl_xor(a2[0], off, 64);
                a2[1] += __shfl_xor(a2[1], off, 64);
                a2[2] += __shfl_xor(a2[2], off, 64);
                a2[3] += __shfl_xor(a2[3], off, 64);
            }
            // rint(sigmoid(t))=1 iff t>0; branch bit = 1 - that. (t==0 -> rint(0.5)=0 -> bit 1.)
            int p = (a0 + b0s > 0.f) ? 0 : 1;
            const float t1 = a1[p] + b1s[p];
            p = p * 2 + ((t1 > 0.f) ? 0 : 1);
            const float t2 = a2[p] + b2s[p];
            p = p * 2 + ((t2 > 0.f) ? 0 : 1);
            if (lane == 0) sleafs[wave * 8 + i] = p;
        }
    } else {
        // ---- repack: 1024 waves x 3 units = 3072 fragment-groups ----
        const int wglob = blk * 4 + (wave - 4);
        const int q = lane >> 4, m = lane & 15;
        #pragma unroll
        for (int u = 0; u < 3; ++u) {
            const int wid = wglob * 3 + u;
            if (wid < 2048) {
                const float* src = (wid < 1024) ? w1a : w1b;
                short*       dst = (wid < 1024) ? pw1a : pw1b;
                const int f = wid & 1023;                       // (l*16+kb)*8+nt
                const int l = f >> 7, kb = (f >> 3) & 15, nt = f & 7;
                const float* s = src + l * 65536 + (kb * 32 + q * 8) * FDIM + nt * 16 + m;
                short8 o;
                #pragma unroll
                for (int j = 0; j < 8; ++j) o[j] = f2bf(s[j * FDIM]);
                *(short8*)(dst + f * 512 + lane * 8) = o;
            } else {
                const int f = wid - 2048;                       // (l*4+kb)*32+nt
                const int l = f >> 7, kb = (f >> 5) & 3, nt = f & 31;
                const float* s = w2 + l * 65536 + (kb * 32 + q * 8) * DIM + nt * 16 + m;
                short8 o;
                #pragma unroll
                for (int j = 0; j < 8; ++j) o[j] = f2bf(s[j * DIM]);
                *(short8*)(pw2 + f * 512 + lane * 8) = o;
            }
        }
    }
    __syncthreads();
    if (t < 8) {
        const int l = t;
        int c = 0;
        for (int i = 0; i < 32; ++i) c += (sleafs[i] == l);
        if (c > 0) {
            int base = atomicAdd(counts + l * 16, c);
            int j = 0;
            for (int i = 0; i < 32; ++i)
                if (sleafs[i] == l) lists[l * N_TOK + base + (j++)] = blk * 32 + i;
        }
    }

    cg::this_grid().sync();

    // ================= post-sync: FFN via work queue =================
    int pre[8]; int tot = 0;
    #pragma unroll
    for (int l = 0; l < 8; ++l) { pre[l] = tot; tot += (counts[l * 16] + BM - 1) / BM; }

    const int qd = lane >> 4, mm = lane & 15;
    for (;;) {
        if (t == 0) s_it = atomicAdd(queue, 1);
        __syncthreads();
        const int it = s_it;
        if (it >= tot) break;
        int leaf = 0;
        #pragma unroll
        for (int l = 1; l < 8; ++l) if (it >= pre[l]) leaf = l;
        const int tile = it - pre[leaf];
        const int cnt  = counts[leaf * 16];

        if (t < BM) {
            const int idx = tile * BM + t;
            toks[t] = lists[leaf * N_TOK + ((idx < cnt) ? idx : cnt - 1)];  // clamp: dup, not stored
        }
        __syncthreads();

        {   // stage x rows -> LDS (already bf16); thread t: row t>>4, 32 cols (64B)
            const int row = t >> 4, c0 = (t & 15) * 32;
            const short8* src = (const short8*)(xbf + (size_t)toks[row] * DIM + c0);
            const short8 s0 = src[0], s1 = src[1], s2 = src[2], s3 = src[3];
            short8* dst = (short8*)&xs[row][c0];
            dst[0] = s0; dst[1] = s1; dst[2] = s2; dst[3] = s3;
        }
        __syncthreads();

        // ---- phase 1: M=32, N=128 (wave owns n-tile = wave), K=512
        floatx4 aA0 = {0,0,0,0}, aA1 = {0,0,0,0}, aB0 = {0,0,0,0}, aB1 = {0,0,0,0};
        const short* pa = pw1a + ((leaf * 16) * 8 + wave) * 512 + lane * 8;
        const short* pb = pw1b + ((leaf * 16) * 8 + wave) * 512 + lane * 8;
        #pragma unroll
        for (int kb = 0; kb < 16; ++kb) {
            const short8 af0 = *(const short8*)&xs[mm][kb * 32 + qd * 8];
            const short8 af1 = *(const short8*)&xs[16 + mm][kb * 32 + qd * 8];
            const short8 ba  = *(const short8*)(pa + kb * (8 * 512));
            const short8 bb  = *(const short8*)(pb + kb * (8 * 512));
            aA0 = __builtin_amdgcn_mfma_f32_16x16x32_bf16(af0, ba, aA0, 0, 0, 0);
            aA1 = __builtin_amdgcn_mfma_f32_16x16x32_bf16(af1, ba, aA1, 0, 0, 0);
            aB0 = __builtin_amdgcn_mfma_f32_16x16x32_bf16(af0, bb, aB0, 0, 0, 0);
            aB1 = __builtin_amdgcn_mfma_f32_16x16x32_bf16(af1, bb, aB1, 0, 0, 0);
        }
        {   // gated bias epilogue -> hs (bf16), C/D layout: col=lane&15, row=qd*4+r
            const int c0 = wave * 16 + mm;
            const float ba_ = b1a[leaf * FDIM + c0];
            const float bb_ = b1b[leaf * FDIM + c0];
            #pragma unroll
            for (int r = 0; r < 4; ++r) {
                const int r0 = qd * 4 + r;
                hs[r0][c0]      = f2bf((aA0[r] + ba_) * (aB0[r] + bb_));
                hs[16 + r0][c0] = f2bf((aA1[r] + ba_) * (aB1[r] + bb_));
            }
        }
        __syncthreads();

        // ---- phase 2: M=32, N=512 (wave owns n-tiles 4w..4w+3), K=128
        floatx4 acc[8];
        #pragma unroll
        for (int j = 0; j < 8; ++j) acc[j] = (floatx4){0, 0, 0, 0};
        #pragma unroll
        for (int kb = 0; kb < 4; ++kb) {
            const short8 af0 = *(const short8*)&hs[mm][kb * 32 + qd * 8];
            const short8 af1 = *(const short8*)&hs[16 + mm][kb * 32 + qd * 8];
            #pragma unroll
            for (int j = 0; j < 4; ++j) {
                const int nt = wave * 4 + j;
                const short8 bf = *(const short8*)(pw2 + (((leaf * 4 + kb) * 32 + nt) * 512) + lane * 8);
                acc[j * 2]     = __builtin_amdgcn_mfma_f32_16x16x32_bf16(af0, bf, acc[j * 2],     0, 0, 0);
                acc[j * 2 + 1] = __builtin_amdgcn_mfma_f32_16x16x32_bf16(af1, bf, acc[j * 2 + 1], 0, 0, 0);
            }
        }
        const int rem = cnt - tile * BM;
        #pragma unroll
        for (int j = 0; j < 4; ++j) {
            const int col = (wave * 4 + j) * 16 + mm;
            const float bias = b2[leaf * DIM + col];
            #pragma unroll
            for (int r = 0; r < 4; ++r) {
                const int r0 = qd * 4 + r;
                if (r0 < rem)      out[toks[r0] * DIM + col]      = acc[j * 2][r]     + bias;
                if (16 + r0 < rem) out[toks[16 + r0] * DIM + col] = acc[j * 2 + 1][r] + bias;
            }
        }
        __syncthreads();   // LDS reuse guard before next queue item
    }
}

extern "C" void kernel_launch(void* const* d_in, const int* in_sizes, int n_in,
                              void* d_out, int out_size, void* d_ws, size_t ws_size,
                              hipStream_t stream) {
    const float* x   = (const float*)d_in[0];
    // d_in[1] = training (forward value identical either way; ignored)
    const float* wn0 = (const float*)d_in[2];
    const float* bn0 = (const float*)d_in[3];
    const float* wn1 = (const float*)d_in[4];
    const float* bn1 = (const float*)d_in[5];
    const float* wn2 = (const float*)d_in[6];
    const float* bn2 = (const float*)d_in[7];
    const float* w1a = (const float*)d_in[8];
    const float* b1a = (const float*)d_in[9];
    const float* w1b = (const float*)d_in[10];
    const float* b1b = (const float*)d_in[11];
    const float* w2  = (const float*)d_in[12];
    const float* b2  = (const float*)d_in[13];
    float* out = (float*)d_out;

    char* ws = (char*)d_ws;
    int*   counts = (int*)(ws);                               // 8 counters, stride 16 ints
    int*   queue  = (int*)(ws + 480);                         // inside the 512B memset region
    int*   lists  = (int*)(ws + 512);                         // 8 x 8192 ints
    short* pw1a   = (short*)(ws + 262656);                    // 1024 frags x 512 bf16
    short* pw1b   = (short*)(ws + 262656 + 1048576);
    short* pw2    = (short*)(ws + 262656 + 2097152);
    short* xbf    = (short*)(ws + 262656 + 3145728);          // 8192 x 512 bf16

    hipMemsetAsync(counts, 0, 512, stream);                   // counts + queue

    void* args[] = {
        (void*)&x, (void*)&wn0, (void*)&bn0, (void*)&wn1, (void*)&bn1,
        (void*)&wn2, (void*)&bn2, (void*)&w1a, (void*)&w1b, (void*)&w2,
        (void*)&b1a, (void*)&b1b, (void*)&b2,
        (void*)&counts, (void*)&lists, (void*)&queue,
        (void*)&pw1a, (void*)&pw1b, (void*)&pw2, (void*)&xbf, (void*)&out
    };
    hipLaunchCooperativeKernel((const void*)k_fused, dim3(256), dim3(512),
                               args, 0, stream);
}

// Round 3
// 125.911 us; speedup vs baseline: 1.4747x; 1.4747x over previous
//
#include <hip/hip_runtime.h>
#include <hip/hip_bf16.h>

#define N_TOK 8192
#define DIM   512
#define FDIM  128
#define BM    32

typedef __attribute__((ext_vector_type(8))) short short8;
typedef __attribute__((ext_vector_type(4))) float floatx4;

__device__ inline short f2bf(float f) {
    union { float f; unsigned u; } v; v.f = f;
    unsigned r = (v.u + 0x7FFF + ((v.u >> 16) & 1)) >> 16;  // RNE, inputs are finite
    return (short)r;
}

// Blocks [0,256): fp32 routing, 8 waves x 4 serial tokens (short dependent
// chain), block-aggregated bucket append; emits bf16 xbf for k_ffn.
// Blocks [256,640): repack w1a/w1b/w2 into bf16 MFMA B-fragment order:
// frag id f -> 512 shorts at pw[f*512 + lane*8 + j]; 8 waves x 1 unit.
__global__ __launch_bounds__(512, 2) void k_prep(
    const float* __restrict__ x,
    const float* __restrict__ wn0, const float* __restrict__ bn0,
    const float* __restrict__ wn1, const float* __restrict__ bn1,
    const float* __restrict__ wn2, const float* __restrict__ bn2,
    const float* __restrict__ w1a, const float* __restrict__ w1b,
    const float* __restrict__ w2,
    int* __restrict__ counts, int* __restrict__ lists,
    short* __restrict__ pw1a, short* __restrict__ pw1b, short* __restrict__ pw2,
    short* __restrict__ xbf)
{
    const int blk = blockIdx.x;
    const int t    = threadIdx.x;
    const int wave = t >> 6, lane = t & 63;
    if (blk < 256) {
        __shared__ int leafs[32];
        const int d0 = lane * 8;
        float v0[8], v1[16], v2[32];
        #pragma unroll
        for (int j = 0; j < 8; ++j)  v0[j] = wn0[d0 + j];
        #pragma unroll
        for (int j = 0; j < 16; ++j) v1[j] = wn1[d0 * 2 + j];   // v1[j*2+c] = wn1[(d0+j)*2+c]
        #pragma unroll
        for (int j = 0; j < 32; ++j) v2[j] = wn2[d0 * 4 + j];   // v2[j*4+c]
        const float b0s = bn0[0];
        const float b1s[2] = {bn1[0], bn1[1]};
        const float b2s[4] = {bn2[0], bn2[1], bn2[2], bn2[3]};
        #pragma unroll
        for (int i = 0; i < 4; ++i) {
            const int tok = blk * 32 + wave * 4 + i;
            const float4* xp = (const float4*)(x + tok * DIM + d0);
            const float4 xa = xp[0], xb = xp[1];
            const float xv[8] = {xa.x, xa.y, xa.z, xa.w, xb.x, xb.y, xb.z, xb.w};
            // bf16 side-channel for k_ffn (same RNE bits k_ffn would produce)
            short8 xo;
            #pragma unroll
            for (int j = 0; j < 8; ++j) xo[j] = f2bf(xv[j]);
            *(short8*)(xbf + (size_t)tok * DIM + d0) = xo;
            float a0 = 0.f, a1[2] = {0.f, 0.f}, a2[4] = {0.f, 0.f, 0.f, 0.f};
            #pragma unroll
            for (int j = 0; j < 8; ++j) {
                a0    += xv[j] * v0[j];
                a1[0] += xv[j] * v1[j * 2];     a1[1] += xv[j] * v1[j * 2 + 1];
                a2[0] += xv[j] * v2[j * 4];     a2[1] += xv[j] * v2[j * 4 + 1];
                a2[2] += xv[j] * v2[j * 4 + 2]; a2[3] += xv[j] * v2[j * 4 + 3];
            }
            #pragma unroll
            for (int off = 32; off >= 1; off >>= 1) {
                a0    += __shfl_xor(a0, off, 64);
                a1[0] += __shfl_xor(a1[0], off, 64);
                a1[1] += __shfl_xor(a1[1], off, 64);
                a2[0] += __shfl_xor(a2[0], off, 64);
                a2[1] += __shfl_xor(a2[1], off, 64);
                a2[2] += __shfl_xor(a2[2], off, 64);
                a2[3] += __shfl_xor(a2[3], off, 64);
            }
            // rint(sigmoid(t))=1 iff t>0; branch bit = 1 - that. (t==0 -> rint(0.5)=0 -> bit 1.)
            int p = (a0 + b0s > 0.f) ? 0 : 1;
            const float t1 = a1[p] + b1s[p];
            p = p * 2 + ((t1 > 0.f) ? 0 : 1);
            const float t2 = a2[p] + b2s[p];
            p = p * 2 + ((t2 > 0.f) ? 0 : 1);
            if (lane == 0) leafs[wave * 4 + i] = p;
        }
        __syncthreads();
        if (t < 8) {
            const int l = t;
            int c = 0;
            for (int i = 0; i < 32; ++i) c += (leafs[i] == l);
            if (c > 0) {
                int base = atomicAdd(counts + l * 16, c);
                int j = 0;
                for (int i = 0; i < 32; ++i)
                    if (leafs[i] == l) lists[l * N_TOK + base + (j++)] = blk * 32 + i;
            }
        }
    } else {
        const int wid  = (blk - 256) * 8 + wave;            // [0,3072)
        const int q = lane >> 4, m = lane & 15;
        if (wid < 2048) {
            const float* src = (wid < 1024) ? w1a : w1b;
            short*       dst = (wid < 1024) ? pw1a : pw1b;
            const int f = wid & 1023;                       // (l*16+kb)*8+nt
            const int l = f >> 7, kb = (f >> 3) & 15, nt = f & 7;
            const float* s = src + l * 65536 + (kb * 32 + q * 8) * FDIM + nt * 16 + m;
            short8 o;
            #pragma unroll
            for (int j = 0; j < 8; ++j) o[j] = f2bf(s[j * FDIM]);
            *(short8*)(dst + f * 512 + lane * 8) = o;
        } else {
            const int f = wid - 2048;                       // (l*4+kb)*32+nt
            const int l = f >> 7, kb = (f >> 5) & 3, nt = f & 31;
            const float* s = w2 + l * 65536 + (kb * 32 + q * 8) * DIM + nt * 16 + m;
            short8 o;
            #pragma unroll
            for (int j = 0; j < 8; ++j) o[j] = f2bf(s[j * DIM]);
            *(short8*)(pw2 + f * 512 + lane * 8) = o;
        }
    }
}

// One block = 32 gathered tokens of one leaf, 8 waves. Each B fragment feeds
// TWO MFMAs (M-tiles rows 0-15 / 16-31). Phase1: h=(x@w1a+b1a)*(x@w1b+b1b),
// wave w owns n-tile w. Phase2: y = h@w2 + b2, wave w owns n-tiles 4w..4w+3.
// VGPR capped at 128 (launch_bounds 512,4) so two blocks co-reside per CU.
__global__ __launch_bounds__(512, 4) void k_ffn(
    const short* __restrict__ xbf,
    const float* __restrict__ b1a, const float* __restrict__ b1b,
    const float* __restrict__ b2,
    const short* __restrict__ pw1a, const short* __restrict__ pw1b,
    const short* __restrict__ pw2,
    const int* __restrict__ counts, const int* __restrict__ lists,
    float* __restrict__ out)
{
    const int leaf = blockIdx.y;
    const int tile = blockIdx.x;
    const int cnt  = counts[leaf * 16];
    if (tile * BM >= cnt) return;

    __shared__ int   toks[BM];
    __shared__ short xs[BM][DIM + 8];    // +8 pad: row stride 1040B -> banks shift 4/row
    __shared__ short hs[BM][FDIM + 8];

    const int t = threadIdx.x;
    if (t < BM) {
        const int idx = tile * BM + t;
        toks[t] = lists[leaf * N_TOK + ((idx < cnt) ? idx : cnt - 1)];  // clamp: dup, not stored
    }
    __syncthreads();

    {   // stage x rows -> LDS (already bf16); thread t: row t>>4, 32 cols (64B)
        const int row = t >> 4, c0 = (t & 15) * 32;
        const short8* src = (const short8*)(xbf + (size_t)toks[row] * DIM + c0);
        const short8 s0 = src[0], s1 = src[1], s2 = src[2], s3 = src[3];
        short8* dst = (short8*)&xs[row][c0];
        dst[0] = s0; dst[1] = s1; dst[2] = s2; dst[3] = s3;
    }
    __syncthreads();

    const int wave = t >> 6, lane = t & 63;
    const int qd = lane >> 4, mm = lane & 15;

    // ---- phase 1: M=32, N=128 (wave owns n-tile = wave), K=512
    floatx4 aA0 = {0,0,0,0}, aA1 = {0,0,0,0}, aB0 = {0,0,0,0}, aB1 = {0,0,0,0};
    const short* pa = pw1a + ((leaf * 16) * 8 + wave) * 512 + lane * 8;
    const short* pb = pw1b + ((leaf * 16) * 8 + wave) * 512 + lane * 8;
    #pragma unroll
    for (int kb = 0; kb < 16; ++kb) {
        const short8 af0 = *(const short8*)&xs[mm][kb * 32 + qd * 8];
        const short8 af1 = *(const short8*)&xs[16 + mm][kb * 32 + qd * 8];
        const short8 ba  = *(const short8*)(pa + kb * (8 * 512));
        const short8 bb  = *(const short8*)(pb + kb * (8 * 512));
        aA0 = __builtin_amdgcn_mfma_f32_16x16x32_bf16(af0, ba, aA0, 0, 0, 0);
        aA1 = __builtin_amdgcn_mfma_f32_16x16x32_bf16(af1, ba, aA1, 0, 0, 0);
        aB0 = __builtin_amdgcn_mfma_f32_16x16x32_bf16(af0, bb, aB0, 0, 0, 0);
        aB1 = __builtin_amdgcn_mfma_f32_16x16x32_bf16(af1, bb, aB1, 0, 0, 0);
    }
    {   // gated bias epilogue -> hs (bf16), C/D layout: col=lane&15, row=qd*4+r
        const int c0 = wave * 16 + mm;
        const float ba_ = b1a[leaf * FDIM + c0];
        const float bb_ = b1b[leaf * FDIM + c0];
        #pragma unroll
        for (int r = 0; r < 4; ++r) {
            const int r0 = qd * 4 + r;
            hs[r0][c0]      = f2bf((aA0[r] + ba_) * (aB0[r] + bb_));
            hs[16 + r0][c0] = f2bf((aA1[r] + ba_) * (aB1[r] + bb_));
        }
    }
    __syncthreads();

    // ---- phase 2: M=32, N=512 (wave owns n-tiles 4w..4w+3), K=128
    floatx4 acc[8];
    #pragma unroll
    for (int j = 0; j < 8; ++j) acc[j] = (floatx4){0, 0, 0, 0};
    #pragma unroll
    for (int kb = 0; kb < 4; ++kb) {
        const short8 af0 = *(const short8*)&hs[mm][kb * 32 + qd * 8];
        const short8 af1 = *(const short8*)&hs[16 + mm][kb * 32 + qd * 8];
        #pragma unroll
        for (int j = 0; j < 4; ++j) {
            const int nt = wave * 4 + j;
            const short8 bf = *(const short8*)(pw2 + (((leaf * 4 + kb) * 32 + nt) * 512) + lane * 8);
            acc[j * 2]     = __builtin_amdgcn_mfma_f32_16x16x32_bf16(af0, bf, acc[j * 2],     0, 0, 0);
            acc[j * 2 + 1] = __builtin_amdgcn_mfma_f32_16x16x32_bf16(af1, bf, acc[j * 2 + 1], 0, 0, 0);
        }
    }
    const int rem = cnt - tile * BM;
    #pragma unroll
    for (int j = 0; j < 4; ++j) {
        const int col = (wave * 4 + j) * 16 + mm;
        const float bias = b2[leaf * DIM + col];
        #pragma unroll
        for (int r = 0; r < 4; ++r) {
            const int r0 = qd * 4 + r;
            if (r0 < rem)      out[toks[r0] * DIM + col]      = acc[j * 2][r]     + bias;
            if (16 + r0 < rem) out[toks[16 + r0] * DIM + col] = acc[j * 2 + 1][r] + bias;
        }
    }
}

extern "C" void kernel_launch(void* const* d_in, const int* in_sizes, int n_in,
                              void* d_out, int out_size, void* d_ws, size_t ws_size,
                              hipStream_t stream) {
    const float* x   = (const float*)d_in[0];
    // d_in[1] = training (forward value identical either way; ignored)
    const float* wn0 = (const float*)d_in[2];
    const float* bn0 = (const float*)d_in[3];
    const float* wn1 = (const float*)d_in[4];
    const float* bn1 = (const float*)d_in[5];
    const float* wn2 = (const float*)d_in[6];
    const float* bn2 = (const float*)d_in[7];
    const float* w1a = (const float*)d_in[8];
    const float* b1a = (const float*)d_in[9];
    const float* w1b = (const float*)d_in[10];
    const float* b1b = (const float*)d_in[11];
    const float* w2  = (const float*)d_in[12];
    const float* b2  = (const float*)d_in[13];
    float* out = (float*)d_out;

    char* ws = (char*)d_ws;
    int*   counts = (int*)(ws);                               // 8 counters, stride 16 ints
    int*   lists  = (int*)(ws + 512);                         // 8 x 8192 ints
    short* pw1a   = (short*)(ws + 262656);                    // 1024 frags x 512 bf16
    short* pw1b   = (short*)(ws + 262656 + 1048576);
    short* pw2    = (short*)(ws + 262656 + 2097152);
    short* xbf    = (short*)(ws + 262656 + 3145728);          // 8192 x 512 bf16

    hipMemsetAsync(counts, 0, 512, stream);
    k_prep<<<640, 512, 0, stream>>>(x, wn0, bn0, wn1, bn1, wn2, bn2,
                                    w1a, w1b, w2, counts, lists, pw1a, pw1b, pw2, xbf);
    k_ffn<<<dim3(256, 8), 512, 0, stream>>>(xbf, b1a, b1b, b2, pw1a, pw1b, pw2,
                                            counts, lists, out);
}